// Round 2
// baseline (1245.423 us; speedup 1.0000x reference)
//
#include <hip/hip_runtime.h>

#define Nn 50000
#define Ee 500000
#define Dd 128

typedef __attribute__((ext_vector_type(8))) short bf16x8;
typedef __attribute__((ext_vector_type(4))) float f32x4;

__device__ inline unsigned short f2bf(float f) {
  unsigned u = __float_as_uint(f);
  unsigned r = u + 0x7FFFu + ((u >> 16) & 1u);
  return (unsigned short)(r >> 16);
}

// ---------------- prep: bf16 weight transposes, bias fuse, x->bf16 ----------
__global__ __launch_bounds__(256) void prep_kernel(
    const float* __restrict__ x, const float* __restrict__ W_types,
    const float* __restrict__ b_types, const float* __restrict__ W_self,
    const float* __restrict__ W_e1, const float* __restrict__ W_e2,
    const float* __restrict__ b_e2,
    unsigned short* __restrict__ xbf, unsigned short* __restrict__ WTt,
    unsigned short* __restrict__ W1T, unsigned short* __restrict__ W2T,
    unsigned short* __restrict__ WsT, float* __restrict__ biasc) {
  int i = blockIdx.x * 256 + threadIdx.x;
  if (i < 65536) {                       // W_types -> [t][n][k] bf16
    int t = i >> 14, rem = i & 16383, n = rem >> 7, k = rem & 127;
    WTt[i] = f2bf(W_types[t * 16384 + k * 128 + n]);
  } else if (i < 81920) {                // W_e1 -> [n][k]
    int j = i - 65536; int n = j >> 7, k = j & 127;
    W1T[j] = f2bf(W_e1[k * 128 + n]);
  } else if (i < 98304) {                // W_e2 -> [n][k]
    int j = i - 81920; int n = j >> 7, k = j & 127;
    W2T[j] = f2bf(W_e2[k * 128 + n]);
  } else if (i < 114688) {               // W_self -> [n][k]
    int j = i - 98304; int n = j >> 7, k = j & 127;
    WsT[j] = f2bf(W_self[k * 128 + n]);
  } else if (i < 115200) {               // biasc[t][n] = b_types + b_e2
    int j = i - 114688; int n = j & 127;
    biasc[j] = b_types[j] + b_e2[n];
  } else if (i < 115200 + Nn * Dd) {     // x -> bf16
    int j = i - 115200;
    xbf[j] = f2bf(x[j]);
  }
}

// ---------------- counting sort of edges by DESTINATION row -----------------
// hist over 50K dest bins -> in-place exclusive scan -> scatter.
__global__ __launch_bounds__(256) void hist_kernel(const int* __restrict__ eidx,
                                                   int* __restrict__ hist) {
  for (int i = blockIdx.x * 256 + threadIdx.x; i < Ee; i += gridDim.x * 256)
    atomicAdd(&hist[eidx[i]], 1);   // eidx[i] = dest row of edge i
}

// single block, in-place exclusive prefix over Nn bins (hc: hist in, cursor out)
__global__ __launch_bounds__(256) void scan_kernel(int* __restrict__ hc) {
  __shared__ int part[256];
  const int tid = threadIdx.x;
  const int per = (Nn + 255) / 256;          // 196
  int base = tid * per, end = min(Nn, base + per);
  int s = 0;
  for (int i = base; i < end; ++i) s += hc[i];
  part[tid] = s;
  __syncthreads();
  if (tid == 0) {
    int run = 0;
    for (int j = 0; j < 256; ++j) { int t = part[j]; part[j] = run; run += t; }
  }
  __syncthreads();
  int run = part[tid];
  for (int i = base; i < end; ++i) { int h = hc[i]; hc[i] = run; run += h; }
}

__global__ __launch_bounds__(256) void scatter_kernel(const int* __restrict__ eidx,
                                                      int* __restrict__ cursor,
                                                      int* __restrict__ sorted_eid) {
  for (int i = blockIdx.x * 256 + threadIdx.x; i < Ee; i += gridDim.x * 256) {
    int p = atomicAdd(&cursor[eidx[i]], 1);
    sorted_eid[p] = i;
  }
}

// ---------------- fused edge kernel: edge MLP + typed GEMM + agg scatter ----
// tile = 64 DEST-SORTED edges; 4 waves, each wave owns a 16-row strip.
// mfma_f32_16x16x32_bf16 layouts (guide-verified):
//   A: lane holds A[m=lane&15][k=quad*8+j]   (16B contiguous in row-major [M][K])
//   B: lane holds B[k=quad*8+j][n=lane&15]   (16B contiguous in BT [N][K])
//   C/D: col=lane&15, row=quad*4+reg
//
// vs prior version:
//  - edges sorted by dest row -> runs of equal dest inside the tile (~7.4
//    unique dests / 64 edges at avg degree 10). Messages land in an LDS f32
//    S[64][132] buffer (union'd with the dead Hs), a serial head-scan finds
//    runs, and ONE atomic per (run,col) writes accum: 64M -> ~7.4M atomics,
//    atomic write traffic 256MB -> ~30MB, per-block accum range contiguous.
//  - GEMM1 becomes up to 4 masked passes (types mixed in tile) — cheap at
//    3.6% MfmaUtil; all 4 waves read identical B fragments (L1-shared).
//  - bijective XCD swizzle so adjacent dest ranges live on one XCD's L2.
__global__ __launch_bounds__(256, 4) void edge_kernel(
    const int* __restrict__ edge_index, const int* __restrict__ edge_type,
    const float* __restrict__ ef, const unsigned short* __restrict__ xbf,
    const unsigned short* __restrict__ WTt, const unsigned short* __restrict__ W1T,
    const unsigned short* __restrict__ W2T, const float* __restrict__ biasc,
    const float* __restrict__ b_e1, const int* __restrict__ sorted_eid,
    float* __restrict__ accum) {
  __shared__ union {
    unsigned short Hs[64][136];   // relu(H) in A-layout (2-way banks only)
    float S[64][132];             // per-edge messages for aggregation
  } U;
  __shared__ int mrow[64];
  __shared__ int mtype[64];
  __shared__ int hpos[65];
  __shared__ int Rcount;

  const int tid = threadIdx.x;
  // bijective XCD-chunk swizzle (m204): XCD k gets a contiguous tile range
  const int nwg = gridDim.x;
  const int q = nwg >> 3, r8 = nwg & 7;
  const int xcd = blockIdx.x & 7, lid = blockIdx.x >> 3;
  const int bswz = (xcd < r8 ? xcd * (q + 1) : r8 * (q + 1) + (xcd - r8) * q) + lid;
  const int tile0 = bswz * 64;

  if (tid < 64) {
    int i = tile0 + tid;
    int r = -1, t = 0;
    if (i < Ee) {
      int ee = sorted_eid[i];
      r = edge_index[ee];        // destination row (sorted key -> ascending)
      t = edge_type[ee];
    }
    mrow[tid] = r;
    mtype[tid] = t;
  }

  const int w = tid >> 6, l = tid & 63, quad = l >> 4, lm = l & 15;
  const int mr = w * 16 + lm;  // this lane's A-fragment row within the tile

  const int i = tile0 + mr;
  const int e = sorted_eid[i < Ee ? i : Ee - 1];   // clamp: tail masked via mrow<0
  const int myt = edge_type[e];
  const int colnode = edge_index[Ee + e];          // source node

  // x A-fragments for GEMM1 — issue early to hide L2 latency
  bf16x8 ax[4];
  {
    const unsigned short* xp = xbf + colnode * Dd + quad * 8;
#pragma unroll
    for (int ks = 0; ks < 4; ++ks) ax[ks] = *(const bf16x8*)(xp + ks * 32);
  }

  // ---- GEMM2: H = ef @ W1 (A direct from global f32, packed in-register) ----
  f32x4 h[8];
#pragma unroll
  for (int c = 0; c < 8; ++c) h[c] = (f32x4){0.f, 0.f, 0.f, 0.f};
  const float* efp = ef + (long long)e * Dd + quad * 8;
#pragma unroll
  for (int ks = 0; ks < 4; ++ks) {
    float4 v0 = *(const float4*)(efp + ks * 32);
    float4 v1 = *(const float4*)(efp + ks * 32 + 4);
    bf16x8 a;
    a[0] = f2bf(v0.x); a[1] = f2bf(v0.y); a[2] = f2bf(v0.z); a[3] = f2bf(v0.w);
    a[4] = f2bf(v1.x); a[5] = f2bf(v1.y); a[6] = f2bf(v1.z); a[7] = f2bf(v1.w);
#pragma unroll
    for (int c = 0; c < 8; ++c) {
      bf16x8 b = *(const bf16x8*)(W1T + (c * 16 + lm) * Dd + ks * 32 + quad * 8);
      h[c] = __builtin_amdgcn_mfma_f32_16x16x32_bf16(a, b, h[c], 0, 0, 0);
    }
  }
  // +b1, relu, write H into Hs strip in A-layout (each wave owns its strip)
#pragma unroll
  for (int c = 0; c < 8; ++c) {
    int n = c * 16 + lm;
    float be = b_e1[n];
#pragma unroll
    for (int r4 = 0; r4 < 4; ++r4) {
      float v = h[c][r4] + be;
      v = v > 0.f ? v : 0.f;
      U.Hs[w * 16 + quad * 4 + r4][n] = f2bf(v);
    }
  }
  __syncthreads();   // #1: Hs + mrow/mtype visible

  // serial run head-scan over the 64 sorted rows (thread 0; hidden under GEMMs)
  if (tid == 0) {
    int Rl = 0, prev = -2, ii = 0;
    for (; ii < 64; ++ii) {
      int rr = mrow[ii];
      if (rr < 0) break;               // invalid tail rows (last tile only)
      if (rr != prev) { hpos[Rl++] = ii; prev = rr; }
    }
    hpos[Rl] = ii;                     // sentinel: end of last run
    Rcount = Rl;
  }

  f32x4 msg[8];
#pragma unroll
  for (int c = 0; c < 8; ++c) msg[c] = (f32x4){0.f, 0.f, 0.f, 0.f};

  // ---- GEMM1: typed transform, masked pass per type present in wave ----
  for (int t = 0; t < 4; ++t) {
    bool mine = (myt == t);
    if (!__any(mine)) continue;
    const unsigned short* Wt = WTt + t * Dd * Dd;
#pragma unroll
    for (int ks = 0; ks < 4; ++ks) {
      bf16x8 a = mine ? ax[ks] : (bf16x8){0, 0, 0, 0, 0, 0, 0, 0};
#pragma unroll
      for (int c = 0; c < 8; ++c) {
        bf16x8 b = *(const bf16x8*)(Wt + (c * 16 + lm) * Dd + ks * 32 + quad * 8);
        msg[c] = __builtin_amdgcn_mfma_f32_16x16x32_bf16(a, b, msg[c], 0, 0, 0);
      }
    }
  }

  // ---- GEMM3: msg += relu(H) @ W2 ----
#pragma unroll
  for (int ks = 0; ks < 4; ++ks) {
    bf16x8 a = *(const bf16x8*)&U.Hs[mr][ks * 32 + quad * 8];
#pragma unroll
    for (int c = 0; c < 8; ++c) {
      bf16x8 b = *(const bf16x8*)(W2T + (c * 16 + lm) * Dd + ks * 32 + quad * 8);
      msg[c] = __builtin_amdgcn_mfma_f32_16x16x32_bf16(a, b, msg[c], 0, 0, 0);
    }
  }
  __syncthreads();   // #2: all Hs reads done before S overwrites the union

  // write per-edge message (+ per-type bias, b_e2 fused) into S
#pragma unroll
  for (int r4 = 0; r4 < 4; ++r4) {
    int m = w * 16 + quad * 4 + r4;
    const float* bc = biasc + mtype[m] * Dd;
#pragma unroll
    for (int c = 0; c < 8; ++c) {
      int n = c * 16 + lm;
      U.S[m][n] = msg[c][r4] + bc[n];
    }
  }
  __syncthreads();   // #3: S complete, hpos/Rcount visible

  // segmented column-sum per dest run, ONE atomic per (run, col)
  const int R = Rcount;
  for (int task = tid; task < (R << 7); task += 256) {
    int run = task >> 7, colv = task & 127;
    int s0 = hpos[run], s1 = hpos[run + 1];
    float s = 0.f;
    for (int rr = s0; rr < s1; ++rr) s += U.S[rr][colv];
    unsafeAtomicAdd(accum + (long long)mrow[s0] * Dd + colv, s);
  }
}

// ---------------- self transform + LayerNorm + ReLU -------------------------
__global__ __launch_bounds__(256) void selfln_kernel(
    const unsigned short* __restrict__ xbf, const unsigned short* __restrict__ WsT,
    const float* __restrict__ b_self, const float* __restrict__ accum,
    const float* __restrict__ ln_g, const float* __restrict__ ln_b,
    float* __restrict__ out) {
  __shared__ unsigned short Axl[64][136];
  __shared__ float S[64][132];
  __shared__ float P1[64][4], P2[64][4];
  __shared__ float MU[64], RS[64];

  const int tid = threadIdx.x;
  const int tile0 = blockIdx.x * 64;
  {
    const int r = tid >> 2, c0 = (tid & 3) * 32;
    int row = tile0 + r;
    if (row < Nn) {
      const uint4* xs = (const uint4*)(xbf + row * Dd + c0);
      uint4* xd = (uint4*)&Axl[r][c0];
      xd[0] = xs[0]; xd[1] = xs[1]; xd[2] = xs[2]; xd[3] = xs[3];
    } else {
      uint4 z = {0, 0, 0, 0};
      uint4* xd = (uint4*)&Axl[r][c0];
      xd[0] = z; xd[1] = z; xd[2] = z; xd[3] = z;
    }
  }
  __syncthreads();

  const int w = tid >> 6, l = tid & 63, quad = l >> 4, lm = l & 15;
  const int mr = w * 16 + lm;
  f32x4 acc[8];
#pragma unroll
  for (int c = 0; c < 8; ++c) acc[c] = (f32x4){0.f, 0.f, 0.f, 0.f};
#pragma unroll
  for (int ks = 0; ks < 4; ++ks) {
    bf16x8 a = *(const bf16x8*)&Axl[mr][ks * 32 + quad * 8];
#pragma unroll
    for (int c = 0; c < 8; ++c) {
      bf16x8 b = *(const bf16x8*)(WsT + (c * 16 + lm) * Dd + ks * 32 + quad * 8);
      acc[c] = __builtin_amdgcn_mfma_f32_16x16x32_bf16(a, b, acc[c], 0, 0, 0);
    }
  }
#pragma unroll
  for (int c = 0; c < 8; ++c) {
    int n = c * 16 + lm;
    float bs = b_self[n];
#pragma unroll
    for (int r4 = 0; r4 < 4; ++r4) {
      int m = w * 16 + quad * 4 + r4;
      int grow = tile0 + m;
      float v = acc[c][r4] + bs;
      if (grow < Nn) v += accum[(long long)grow * Dd + n];
      S[m][n] = v;
    }
  }
  __syncthreads();
  {
    const int r = tid >> 2, sgi = tid & 3, c0 = sgi * 32;
    float s1 = 0.f, s2 = 0.f;
#pragma unroll
    for (int j = 0; j < 32; ++j) { float v = S[r][c0 + j]; s1 += v; s2 += v * v; }
    P1[r][sgi] = s1; P2[r][sgi] = s2;
  }
  __syncthreads();
  if (tid < 64) {
    float s1 = P1[tid][0] + P1[tid][1] + P1[tid][2] + P1[tid][3];
    float s2 = P2[tid][0] + P2[tid][1] + P2[tid][2] + P2[tid][3];
    float mu = s1 * (1.f / 128.f);
    float var = s2 * (1.f / 128.f) - mu * mu;
    MU[tid] = mu;
    RS[tid] = rsqrtf(var + 1e-5f);
  }
  __syncthreads();
  {
    const int r = tid >> 2, c0 = (tid & 3) * 32;
    int row = tile0 + r;
    if (row < Nn) {
      float mu = MU[r], rs = RS[r];
      float* op = out + (long long)row * Dd + c0;
#pragma unroll
      for (int j = 0; j < 32; ++j) {
        float v = (S[r][c0 + j] - mu) * rs * ln_g[c0 + j] + ln_b[c0 + j];
        op[j] = v > 0.f ? v : 0.f;
      }
    }
  }
}

// ---------------- launch ----------------------------------------------------
extern "C" void kernel_launch(void* const* d_in, const int* in_sizes, int n_in,
                              void* d_out, int out_size, void* d_ws, size_t ws_size,
                              hipStream_t stream) {
  (void)in_sizes; (void)n_in; (void)out_size; (void)ws_size;
  const float* x       = (const float*)d_in[0];
  const int*   eidx    = (const int*)d_in[1];
  const int*   etype   = (const int*)d_in[2];
  const float* ef      = (const float*)d_in[3];
  const float* W_types = (const float*)d_in[4];
  const float* b_types = (const float*)d_in[5];
  const float* W_self  = (const float*)d_in[6];
  const float* b_self  = (const float*)d_in[7];
  const float* W_e1    = (const float*)d_in[8];
  const float* b_e1    = (const float*)d_in[9];
  const float* W_e2    = (const float*)d_in[10];
  const float* b_e2    = (const float*)d_in[11];
  const float* ln_g    = (const float*)d_in[12];
  const float* ln_b    = (const float*)d_in[13];
  float* out = (float*)d_out;

  char* ws = (char*)d_ws;
  // layout (512B-aligned regions):
  //   [0)          hist/cursor  (Nn ints = 200,000B, pad to 200,704; in-place scan)
  //   [200704)     accum        N*D f32 = 25,600,000B
  //   [25800704)   xbf          12,800,000B
  //   [38600704)   WTt..biasc   131072+32768*3+2048
  //   [+...]       sorted_eid   E*4 = 2,000,000B
  int*            histc  = (int*)ws;
  float*          accum  = (float*)(ws + 200704);
  unsigned short* xbf    = (unsigned short*)(ws + 200704 + 25600000);
  unsigned short* WTt    = (unsigned short*)(ws + 200704 + 25600000 + 12800000);
  unsigned short* W1T    = WTt + 4 * 128 * 128;
  unsigned short* W2T    = W1T + 128 * 128;
  unsigned short* WsT    = W2T + 128 * 128;
  float*          biasc  = (float*)(WsT + 128 * 128);
  int*            sorted = (int*)((char*)biasc + 2048);

  // zero hist + accum (contiguous)
  hipMemsetAsync(ws, 0, 200704 + (size_t)Nn * Dd * 4, stream);

  prep_kernel<<<25450, 256, 0, stream>>>(x, W_types, b_types, W_self, W_e1, W_e2,
                                         b_e2, xbf, WTt, W1T, W2T, WsT, biasc);
  hist_kernel<<<512, 256, 0, stream>>>(eidx, histc);
  scan_kernel<<<1, 256, 0, stream>>>(histc);
  scatter_kernel<<<512, 256, 0, stream>>>(eidx, histc, sorted);
  edge_kernel<<<(Ee + 63) / 64, 256, 0, stream>>>(eidx, etype, ef, xbf, WTt, W1T,
                                                  W2T, biasc, b_e1, sorted, accum);
  selfln_kernel<<<(Nn + 63) / 64, 256, 0, stream>>>(xbf, WsT, b_self, accum, ln_g,
                                                    ln_b, out);
}

// Round 3
// 700.246 us; speedup vs baseline: 1.7786x; 1.7786x over previous
//
#include <hip/hip_runtime.h>

#define Nn 50000
#define Ee 500000
#define Dd 128

typedef __attribute__((ext_vector_type(8))) short bf16x8;
typedef __attribute__((ext_vector_type(4))) float f32x4;

__device__ inline unsigned short f2bf(float f) {
  unsigned u = __float_as_uint(f);
  unsigned r = u + 0x7FFFu + ((u >> 16) & 1u);
  return (unsigned short)(r >> 16);
}

// ---------------- prep: bf16 weight transposes, bias fuse, x->bf16 ----------
__global__ __launch_bounds__(256) void prep_kernel(
    const float* __restrict__ x, const float* __restrict__ W_types,
    const float* __restrict__ b_types, const float* __restrict__ W_self,
    const float* __restrict__ W_e1, const float* __restrict__ W_e2,
    const float* __restrict__ b_e2,
    unsigned short* __restrict__ xbf, unsigned short* __restrict__ WTt,
    unsigned short* __restrict__ W1T, unsigned short* __restrict__ W2T,
    unsigned short* __restrict__ WsT, float* __restrict__ biasc) {
  int i = blockIdx.x * 256 + threadIdx.x;
  if (i < 65536) {                       // W_types -> [t][n][k] bf16
    int t = i >> 14, rem = i & 16383, n = rem >> 7, k = rem & 127;
    WTt[i] = f2bf(W_types[t * 16384 + k * 128 + n]);
  } else if (i < 81920) {                // W_e1 -> [n][k]
    int j = i - 65536; int n = j >> 7, k = j & 127;
    W1T[j] = f2bf(W_e1[k * 128 + n]);
  } else if (i < 98304) {                // W_e2 -> [n][k]
    int j = i - 81920; int n = j >> 7, k = j & 127;
    W2T[j] = f2bf(W_e2[k * 128 + n]);
  } else if (i < 114688) {               // W_self -> [n][k]
    int j = i - 98304; int n = j >> 7, k = j & 127;
    WsT[j] = f2bf(W_self[k * 128 + n]);
  } else if (i < 115200) {               // biasc[t][n] = b_types + b_e2
    int j = i - 114688; int n = j & 127;
    biasc[j] = b_types[j] + b_e2[n];
  } else if (i < 115200 + Nn * Dd) {     // x -> bf16
    int j = i - 115200;
    xbf[j] = f2bf(x[j]);
  }
}

// ---------------- counting sort of edges by TYPE (4 buckets) ----------------
__global__ __launch_bounds__(256) void hist_kernel(const int* __restrict__ et,
                                                   int* __restrict__ hist) {
  __shared__ int h[4];
  if (threadIdx.x < 4) h[threadIdx.x] = 0;
  __syncthreads();
  for (int i = blockIdx.x * 256 + threadIdx.x; i < Ee; i += gridDim.x * 256)
    atomicAdd(&h[et[i]], 1);
  __syncthreads();
  if (threadIdx.x < 4) atomicAdd(&hist[threadIdx.x], h[threadIdx.x]);
}

__global__ void prefix_kernel(const int* __restrict__ hist, int* __restrict__ cursor) {
  if (threadIdx.x == 0) {
    int s = 0;
    for (int t = 0; t < 4; ++t) { cursor[t] = s; s += hist[t]; }
  }
}

__global__ __launch_bounds__(256) void scatter_kernel(const int* __restrict__ et,
                                                      int* __restrict__ cursor,
                                                      int* __restrict__ sorted_eid) {
  __shared__ int lc[4], bb[4];
  if (threadIdx.x < 4) lc[threadIdx.x] = 0;
  __syncthreads();
  int per = (Ee + gridDim.x - 1) / gridDim.x;
  int s = blockIdx.x * per;
  int e = min(Ee, s + per);
  for (int i = s + (int)threadIdx.x; i < e; i += 256) atomicAdd(&lc[et[i]], 1);
  __syncthreads();
  if (threadIdx.x < 4) bb[threadIdx.x] = atomicAdd(&cursor[threadIdx.x], lc[threadIdx.x]);
  __syncthreads();
  if (threadIdx.x < 4) lc[threadIdx.x] = bb[threadIdx.x];
  __syncthreads();
  for (int i = s + (int)threadIdx.x; i < e; i += 256) {
    int p = atomicAdd(&lc[et[i]], 1);
    sorted_eid[p] = i;
  }
}

// ---- LDS weight staging: 32KB [128 rows][256B], XOR-swizzled ---------------
// write: chunk (row, off16) -> byte  row*256 + ((off16<<4) ^ ((row&7)<<4))
// read (fragment row, base B=ks*64+quad*16): byte row*256 + (B ^ ((row&7)<<4))
// Reads: 16 lanes/quad hit 8 distinct 16B slots -> 2-way (free, m136).
// Staging: lane-contiguous 16B global chunks -> coalesced dwordx4; writes
// bank-balanced.
__device__ inline void stageW(const unsigned short* __restrict__ Wg,
                              unsigned short* __restrict__ Wb, int tid) {
  const uint4* src = (const uint4*)Wg;
#pragma unroll
  for (int c = 0; c < 8; ++c) {
    int ch = c * 256 + tid;             // 2048 chunks of 16B
    int row = ch >> 4;
    int off = (ch & 15) << 4;
    *(uint4*)((char*)Wb + row * 256 + (off ^ ((row & 7) << 4))) = src[ch];
  }
}

// ---------------- fused edge kernel: edge MLP + typed GEMM + scatter --------
// tile = 64 TYPE-SORTED edges; 4 waves, each wave owns a 16-row strip.
// mfma_f32_16x16x32_bf16 layouts (guide-verified):
//   A: lane holds A[m=lane&15][k=quad*8+j]   (16B contiguous in row-major [M][K])
//   B: lane holds B[k=quad*8+j][n=lane&15]   (16B contiguous in BT [N][K])
//   C/D: col=lane&15, row=quad*4+reg
//
// vs R1 (546us): weight matrices are staged into a single rotating 32KB LDS
// buffer once per GEMM phase; fragment B-reads become ds_read_b128 (~96
// LDS reads/wave) instead of ~1536 L1/L2 line-requests/wave through the
// per-CU TA. Everything else identical to R1 (type-sort, direct ax/ef
// gathers, per-edge atomics).
__global__ __launch_bounds__(256, 3) void edge_kernel(
    const int* __restrict__ edge_index, const int* __restrict__ edge_type,
    const float* __restrict__ ef, const unsigned short* __restrict__ xbf,
    const unsigned short* __restrict__ WTt, const unsigned short* __restrict__ W1T,
    const unsigned short* __restrict__ W2T, const float* __restrict__ biasc,
    const float* __restrict__ b_e1, const int* __restrict__ sorted_eid,
    float* __restrict__ accum) {
  __shared__ __align__(16) unsigned short Wb[16384];   // 32KB rotating W buffer
  __shared__ unsigned short Hs[64][136];               // relu(H), A-layout
  __shared__ int mrow[64];
  __shared__ int mtype[64];
  __shared__ int tmask_s;

  const int tid = threadIdx.x;
  const int tile0 = blockIdx.x * 64;

  if (tid < 64) {                    // single wave: LDS ops in program order
    if (tid == 0) tmask_s = 0;
    int i = tile0 + tid;
    int r = -1, t = -1;
    if (i < Ee) {
      int ee = sorted_eid[i];
      r = edge_index[ee];            // destination row
      t = edge_type[ee];
    }
    mrow[tid] = r;
    mtype[tid] = t;
    if (t >= 0) atomicOr(&tmask_s, 1 << t);
  }

  const int w = tid >> 6, l = tid & 63, quad = l >> 4, lm = l & 15;
  const int mr = w * 16 + lm;        // this lane's A-fragment row within tile
  const int rswz = (lm & 7) << 4;    // fragment-read swizzle (row&7 == lm&7)

  const int i = tile0 + mr;
  const int e = sorted_eid[i < Ee ? i : Ee - 1];   // clamp: tail masked via mrow<0
  const int myt = edge_type[e];
  const int colnode = edge_index[Ee + e];          // source node

  // x A-fragments for GEMM1 — issue early to hide L2/L3 latency
  bf16x8 ax[4];
  {
    const unsigned short* xp = xbf + colnode * Dd + quad * 8;
#pragma unroll
    for (int ks = 0; ks < 4; ++ks) ax[ks] = *(const bf16x8*)(xp + ks * 32);
  }

  stageW(W1T, Wb, tid);              // overlaps with the gathers above
  __syncthreads();                   // W1 staged; mrow/mtype/tmask visible

  // ---- GEMM2: H = ef @ W1 (A direct from global f32, B from LDS) ----
  f32x4 h[8];
#pragma unroll
  for (int c = 0; c < 8; ++c) h[c] = (f32x4){0.f, 0.f, 0.f, 0.f};
  const float* efp = ef + (long long)e * Dd + quad * 8;
#pragma unroll
  for (int ks = 0; ks < 4; ++ks) {
    float4 v0 = *(const float4*)(efp + ks * 32);
    float4 v1 = *(const float4*)(efp + ks * 32 + 4);
    bf16x8 a;
    a[0] = f2bf(v0.x); a[1] = f2bf(v0.y); a[2] = f2bf(v0.z); a[3] = f2bf(v0.w);
    a[4] = f2bf(v1.x); a[5] = f2bf(v1.y); a[6] = f2bf(v1.z); a[7] = f2bf(v1.w);
    const int fb = (ks * 64 + quad * 16) ^ rswz;
#pragma unroll
    for (int c = 0; c < 8; ++c) {
      bf16x8 b = *(const bf16x8*)((const char*)Wb + (c * 16 + lm) * 256 + fb);
      h[c] = __builtin_amdgcn_mfma_f32_16x16x32_bf16(a, b, h[c], 0, 0, 0);
    }
  }
  // +b1, relu, write H into Hs strip in A-layout (each wave owns its strip)
#pragma unroll
  for (int c = 0; c < 8; ++c) {
    int n = c * 16 + lm;
    float be = b_e1[n];
#pragma unroll
    for (int r4 = 0; r4 < 4; ++r4) {
      float v = h[c][r4] + be;
      v = v > 0.f ? v : 0.f;
      Hs[w * 16 + quad * 4 + r4][n] = f2bf(v);
    }
  }
  __syncthreads();                   // Hs ready; all GEMM2 Wb reads done

  stageW(W2T, Wb, tid);
  __syncthreads();                   // W2 staged

  f32x4 msg[8];
#pragma unroll
  for (int c = 0; c < 8; ++c) msg[c] = (f32x4){0.f, 0.f, 0.f, 0.f};

  // ---- GEMM3: msg = relu(H) @ W2 (A from Hs, B from LDS) ----
#pragma unroll
  for (int ks = 0; ks < 4; ++ks) {
    bf16x8 a = *(const bf16x8*)&Hs[mr][ks * 32 + quad * 8];
    const int fb = (ks * 64 + quad * 16) ^ rswz;
#pragma unroll
    for (int c = 0; c < 8; ++c) {
      bf16x8 b = *(const bf16x8*)((const char*)Wb + (c * 16 + lm) * 256 + fb);
      msg[c] = __builtin_amdgcn_mfma_f32_16x16x32_bf16(a, b, msg[c], 0, 0, 0);
    }
  }
  __syncthreads();                   // all GEMM3 Wb reads done

  // ---- GEMM1: typed transform; stage + masked pass per type present ----
  const int tmask = tmask_s;         // block-uniform
  for (int t = 0; t < 4; ++t) {
    if (!(tmask & (1 << t))) continue;
    stageW(WTt + t * Dd * Dd, Wb, tid);
    __syncthreads();                 // Wt staged (uniform: tmask block-wide)
    bool mine = (myt == t);
    if (__any(mine)) {
#pragma unroll
      for (int ks = 0; ks < 4; ++ks) {
        bf16x8 a = mine ? ax[ks] : (bf16x8){0, 0, 0, 0, 0, 0, 0, 0};
        const int fb = (ks * 64 + quad * 16) ^ rswz;
#pragma unroll
        for (int c = 0; c < 8; ++c) {
          bf16x8 b = *(const bf16x8*)((const char*)Wb + (c * 16 + lm) * 256 + fb);
          msg[c] = __builtin_amdgcn_mfma_f32_16x16x32_bf16(a, b, msg[c], 0, 0, 0);
        }
      }
    }
    __syncthreads();                 // Wb reads done before next restage
  }

  // epilogue: + per-type bias (+b_e2 fused) and atomic scatter to accum[row]
#pragma unroll
  for (int r4 = 0; r4 < 4; ++r4) {
    int m = w * 16 + quad * 4 + r4;
    int rn = mrow[m];
    if (rn < 0) continue;
    int t = mtype[m];
    float* dst = accum + (long long)rn * Dd;
    const float* bc = biasc + t * Dd;
#pragma unroll
    for (int c = 0; c < 8; ++c) {
      int n = c * 16 + lm;
      unsafeAtomicAdd(dst + n, msg[c][r4] + bc[n]);
    }
  }
}

// ---------------- self transform + LayerNorm + ReLU -------------------------
__global__ __launch_bounds__(256) void selfln_kernel(
    const unsigned short* __restrict__ xbf, const unsigned short* __restrict__ WsT,
    const float* __restrict__ b_self, const float* __restrict__ accum,
    const float* __restrict__ ln_g, const float* __restrict__ ln_b,
    float* __restrict__ out) {
  __shared__ unsigned short Axl[64][136];
  __shared__ float S[64][132];
  __shared__ float P1[64][4], P2[64][4];
  __shared__ float MU[64], RS[64];

  const int tid = threadIdx.x;
  const int tile0 = blockIdx.x * 64;
  {
    const int r = tid >> 2, c0 = (tid & 3) * 32;
    int row = tile0 + r;
    if (row < Nn) {
      const uint4* xs = (const uint4*)(xbf + row * Dd + c0);
      uint4* xd = (uint4*)&Axl[r][c0];
      xd[0] = xs[0]; xd[1] = xs[1]; xd[2] = xs[2]; xd[3] = xs[3];
    } else {
      uint4 z = {0, 0, 0, 0};
      uint4* xd = (uint4*)&Axl[r][c0];
      xd[0] = z; xd[1] = z; xd[2] = z; xd[3] = z;
    }
  }
  __syncthreads();

  const int w = tid >> 6, l = tid & 63, quad = l >> 4, lm = l & 15;
  const int mr = w * 16 + lm;
  f32x4 acc[8];
#pragma unroll
  for (int c = 0; c < 8; ++c) acc[c] = (f32x4){0.f, 0.f, 0.f, 0.f};
#pragma unroll
  for (int ks = 0; ks < 4; ++ks) {
    bf16x8 a = *(const bf16x8*)&Axl[mr][ks * 32 + quad * 8];
#pragma unroll
    for (int c = 0; c < 8; ++c) {
      bf16x8 b = *(const bf16x8*)(WsT + (c * 16 + lm) * Dd + ks * 32 + quad * 8);
      acc[c] = __builtin_amdgcn_mfma_f32_16x16x32_bf16(a, b, acc[c], 0, 0, 0);
    }
  }
#pragma unroll
  for (int c = 0; c < 8; ++c) {
    int n = c * 16 + lm;
    float bs = b_self[n];
#pragma unroll
    for (int r4 = 0; r4 < 4; ++r4) {
      int m = w * 16 + quad * 4 + r4;
      int grow = tile0 + m;
      float v = acc[c][r4] + bs;
      if (grow < Nn) v += accum[(long long)grow * Dd + n];
      S[m][n] = v;
    }
  }
  __syncthreads();
  {
    const int r = tid >> 2, sgi = tid & 3, c0 = sgi * 32;
    float s1 = 0.f, s2 = 0.f;
#pragma unroll
    for (int j = 0; j < 32; ++j) { float v = S[r][c0 + j]; s1 += v; s2 += v * v; }
    P1[r][sgi] = s1; P2[r][sgi] = s2;
  }
  __syncthreads();
  if (tid < 64) {
    float s1 = P1[tid][0] + P1[tid][1] + P1[tid][2] + P1[tid][3];
    float s2 = P2[tid][0] + P2[tid][1] + P2[tid][2] + P2[tid][3];
    float mu = s1 * (1.f / 128.f);
    float var = s2 * (1.f / 128.f) - mu * mu;
    MU[tid] = mu;
    RS[tid] = rsqrtf(var + 1e-5f);
  }
  __syncthreads();
  {
    const int r = tid >> 2, c0 = (tid & 3) * 32;
    int row = tile0 + r;
    if (row < Nn) {
      float mu = MU[r], rs = RS[r];
      float* op = out + (long long)row * Dd + c0;
#pragma unroll
      for (int j = 0; j < 32; ++j) {
        float v = (S[r][c0 + j] - mu) * rs * ln_g[c0 + j] + ln_b[c0 + j];
        op[j] = v > 0.f ? v : 0.f;
      }
    }
  }
}

// ---------------- launch ----------------------------------------------------
extern "C" void kernel_launch(void* const* d_in, const int* in_sizes, int n_in,
                              void* d_out, int out_size, void* d_ws, size_t ws_size,
                              hipStream_t stream) {
  (void)in_sizes; (void)n_in; (void)out_size; (void)ws_size;
  const float* x       = (const float*)d_in[0];
  const int*   eidx    = (const int*)d_in[1];
  const int*   etype   = (const int*)d_in[2];
  const float* ef      = (const float*)d_in[3];
  const float* W_types = (const float*)d_in[4];
  const float* b_types = (const float*)d_in[5];
  const float* W_self  = (const float*)d_in[6];
  const float* b_self  = (const float*)d_in[7];
  const float* W_e1    = (const float*)d_in[8];
  const float* b_e1    = (const float*)d_in[9];
  const float* W_e2    = (const float*)d_in[10];
  const float* b_e2    = (const float*)d_in[11];
  const float* ln_g    = (const float*)d_in[12];
  const float* ln_b    = (const float*)d_in[13];
  float* out = (float*)d_out;

  char* ws = (char*)d_ws;
  // layout (all offsets 512B-aligned)
  int*            ints   = (int*)ws;                              // [0..3] hist, [4..7] cursor
  float*          accum  = (float*)(ws + 512);                    // N*D f32 = 25,600,000 B
  unsigned short* xbf    = (unsigned short*)(ws + 512 + 25600000);            // 12,800,000 B
  unsigned short* WTt    = (unsigned short*)(ws + 512 + 25600000 + 12800000); // 131,072 B
  unsigned short* W1T    = WTt + 4 * 128 * 128;
  unsigned short* W2T    = W1T + 128 * 128;
  unsigned short* WsT    = W2T + 128 * 128;
  float*          biasc  = (float*)(WsT + 128 * 128);             // 2,048 B
  int*            sorted = (int*)((char*)biasc + 2048);           // E*4 = 2,000,000 B

  hipMemsetAsync(ws, 0, 512 + (size_t)Nn * Dd * 4, stream);  // hist+cursor+accum

  prep_kernel<<<25450, 256, 0, stream>>>(x, W_types, b_types, W_self, W_e1, W_e2,
                                         b_e2, xbf, WTt, W1T, W2T, WsT, biasc);
  hist_kernel<<<512, 256, 0, stream>>>(etype, ints);
  prefix_kernel<<<1, 64, 0, stream>>>(ints, ints + 4);
  scatter_kernel<<<512, 256, 0, stream>>>(etype, ints + 4, sorted);
  edge_kernel<<<(Ee + 63) / 64, 256, 0, stream>>>(eidx, etype, ef, xbf, WTt, W1T,
                                                  W2T, biasc, b_e1, sorted, accum);
  selfln_kernel<<<(Nn + 63) / 64, 256, 0, stream>>>(xbf, WsT, b_self, accum, ln_g,
                                                    ln_b, out);
}

// Round 4
// 638.271 us; speedup vs baseline: 1.9512x; 1.0971x over previous
//
#include <hip/hip_runtime.h>

#define Nn 50000
#define Ee 500000
#define Dd 128

typedef __attribute__((ext_vector_type(8))) short bf16x8;
typedef __attribute__((ext_vector_type(4))) float f32x4;

__device__ inline unsigned short f2bf(float f) {
  unsigned u = __float_as_uint(f);
  unsigned r = u + 0x7FFFu + ((u >> 16) & 1u);
  return (unsigned short)(r >> 16);
}

// ---------------- prep: bf16 weight transposes, bias fuse, x->bf16 ----------
__global__ __launch_bounds__(256) void prep_kernel(
    const float* __restrict__ x, const float* __restrict__ W_types,
    const float* __restrict__ b_types, const float* __restrict__ W_self,
    const float* __restrict__ W_e1, const float* __restrict__ W_e2,
    const float* __restrict__ b_e2,
    unsigned short* __restrict__ xbf, unsigned short* __restrict__ WTt,
    unsigned short* __restrict__ W1T, unsigned short* __restrict__ W2T,
    unsigned short* __restrict__ WsT, float* __restrict__ biasc) {
  int i = blockIdx.x * 256 + threadIdx.x;
  if (i < 65536) {                       // W_types -> [t][n][k] bf16
    int t = i >> 14, rem = i & 16383, n = rem >> 7, k = rem & 127;
    WTt[i] = f2bf(W_types[t * 16384 + k * 128 + n]);
  } else if (i < 81920) {                // W_e1 -> [n][k]
    int j = i - 65536; int n = j >> 7, k = j & 127;
    W1T[j] = f2bf(W_e1[k * 128 + n]);
  } else if (i < 98304) {                // W_e2 -> [n][k]
    int j = i - 81920; int n = j >> 7, k = j & 127;
    W2T[j] = f2bf(W_e2[k * 128 + n]);
  } else if (i < 114688) {               // W_self -> [n][k]
    int j = i - 98304; int n = j >> 7, k = j & 127;
    WsT[j] = f2bf(W_self[k * 128 + n]);
  } else if (i < 115200) {               // biasc[t][n] = b_types + b_e2
    int j = i - 114688; int n = j & 127;
    biasc[j] = b_types[j] + b_e2[n];
  } else if (i < 115200 + Nn * Dd) {     // x -> bf16
    int j = i - 115200;
    xbf[j] = f2bf(x[j]);
  }
}

// ---------------- counting sort of edges by TYPE (4 buckets) ----------------
__global__ __launch_bounds__(256) void hist_kernel(const int* __restrict__ et,
                                                   int* __restrict__ hist) {
  __shared__ int h[4];
  if (threadIdx.x < 4) h[threadIdx.x] = 0;
  __syncthreads();
  for (int i = blockIdx.x * 256 + threadIdx.x; i < Ee; i += gridDim.x * 256)
    atomicAdd(&h[et[i]], 1);
  __syncthreads();
  if (threadIdx.x < 4) atomicAdd(&hist[threadIdx.x], h[threadIdx.x]);
}

__global__ void prefix_kernel(const int* __restrict__ hist, int* __restrict__ cursor) {
  if (threadIdx.x == 0) {
    int s = 0;
    for (int t = 0; t < 4; ++t) { cursor[t] = s; s += hist[t]; }
  }
}

__global__ __launch_bounds__(256) void scatter_kernel(const int* __restrict__ et,
                                                      int* __restrict__ cursor,
                                                      int* __restrict__ sorted_eid) {
  __shared__ int lc[4], bb[4];
  if (threadIdx.x < 4) lc[threadIdx.x] = 0;
  __syncthreads();
  int per = (Ee + gridDim.x - 1) / gridDim.x;
  int s = blockIdx.x * per;
  int e = min(Ee, s + per);
  for (int i = s + (int)threadIdx.x; i < e; i += 256) atomicAdd(&lc[et[i]], 1);
  __syncthreads();
  if (threadIdx.x < 4) bb[threadIdx.x] = atomicAdd(&cursor[threadIdx.x], lc[threadIdx.x]);
  __syncthreads();
  if (threadIdx.x < 4) lc[threadIdx.x] = bb[threadIdx.x];
  __syncthreads();
  for (int i = s + (int)threadIdx.x; i < e; i += 256) {
    int p = atomicAdd(&lc[et[i]], 1);
    sorted_eid[p] = i;
  }
}

// ---- LDS weight staging: 32KB [128 rows][256B], XOR-swizzled ---------------
__device__ inline void stageW(const unsigned short* __restrict__ Wg,
                              unsigned short* __restrict__ Wb, int tid) {
  const uint4* src = (const uint4*)Wg;
#pragma unroll
  for (int c = 0; c < 8; ++c) {
    int ch = c * 256 + tid;             // 2048 chunks of 16B
    int row = ch >> 4;
    int off = (ch & 15) << 4;
    *(uint4*)((char*)Wb + row * 256 + (off ^ ((row & 7) << 4))) = src[ch];
  }
}

// ---------------- fused edge kernel: edge MLP + typed GEMM + scatter --------
// tile = 64 TYPE-SORTED edges; 4 waves, each wave owns a 16-row strip.
// mfma_f32_16x16x32_bf16 layouts (guide-verified):
//   A: lane holds A[m=lane&15][k=quad*8+j]   (16B contiguous in row-major [M][K])
//   B: lane holds B[k=quad*8+j][n=lane&15]   (16B contiguous in BT [N][K])
//   C/D: col=lane&15, row=quad*4+reg
// A- and B-fragments carry identically-shaped per-lane data (row lane&15,
// k-chunk quad*8), so swapping mfma args transposes the output.
//
// vs R3: GEMM2 runs operand-SWAPPED (H^T = W1T-rows x ef^T), so each lane
// ends up holding its OWN edge's full H row (n = c*16+quad*4+r4). Bias+relu+
// bf16-pack happen in registers; GEMM3's A-fragments are rebuilt from
// quad-mates via __shfl (8 bpermute + 4 selects per K-step). The 17.4KB Hs
// buffer and its barrier phase disappear: LDS 51.2 -> 33.3KB = 4 blocks/CU.
__global__ __launch_bounds__(256, 4) void edge_kernel(
    const int* __restrict__ edge_index, const int* __restrict__ edge_type,
    const float* __restrict__ ef, const unsigned short* __restrict__ xbf,
    const unsigned short* __restrict__ WTt, const unsigned short* __restrict__ W1T,
    const unsigned short* __restrict__ W2T, const float* __restrict__ biasc,
    const float* __restrict__ b_e1, const int* __restrict__ sorted_eid,
    float* __restrict__ accum) {
  __shared__ __align__(16) unsigned short Wb[16384];   // 32KB rotating W buffer
  __shared__ int mrow[64];
  __shared__ int mtype[64];
  __shared__ int tmask_s;

  const int tid = threadIdx.x;
  const int tile0 = blockIdx.x * 64;

  if (tid < 64) {                    // single wave: LDS ops in program order
    if (tid == 0) tmask_s = 0;
    int i = tile0 + tid;
    int r = -1, t = -1;
    if (i < Ee) {
      int ee = sorted_eid[i];
      r = edge_index[ee];            // destination row
      t = edge_type[ee];
    }
    mrow[tid] = r;
    mtype[tid] = t;
    if (t >= 0) atomicOr(&tmask_s, 1 << t);
  }

  const int w = tid >> 6, l = tid & 63, quad = l >> 4, lm = l & 15;
  const int mr = w * 16 + lm;        // this lane's edge row within tile
  const int rswz = (lm & 7) << 4;    // fragment-read swizzle (row&7 == lm&7)

  const int i = tile0 + mr;
  const int e = sorted_eid[i < Ee ? i : Ee - 1];   // clamp: tail masked via mrow<0
  const int myt = edge_type[e];
  const int colnode = edge_index[Ee + e];          // source node

  // x A-fragments for GEMM1 — issue early to hide L2/L3 latency
  bf16x8 ax[4];
  {
    const unsigned short* xp = xbf + colnode * Dd + quad * 8;
#pragma unroll
    for (int ks = 0; ks < 4; ++ks) ax[ks] = *(const bf16x8*)(xp + ks * 32);
  }
  // raw ef row (f32) — issued pre-barrier so HBM latency hides under staging
  float4 efr[8];
  {
    const float* efp = ef + (long long)e * Dd + quad * 8;
#pragma unroll
    for (int j = 0; j < 8; ++j)
      efr[j] = *(const float4*)(efp + (j >> 1) * 32 + (j & 1) * 4);
  }

  stageW(W1T, Wb, tid);              // overlaps with the gathers above
  __syncthreads();                   // #1: W1 staged; mrow/mtype/tmask visible

  // pack ef to bf16 fragments (loads drained by barrier)
  bf16x8 efrag[4];
#pragma unroll
  for (int ks = 0; ks < 4; ++ks) {
    float4 v0 = efr[2 * ks], v1 = efr[2 * ks + 1];
    bf16x8 a;
    a[0] = f2bf(v0.x); a[1] = f2bf(v0.y); a[2] = f2bf(v0.z); a[3] = f2bf(v0.w);
    a[4] = f2bf(v1.x); a[5] = f2bf(v1.y); a[6] = f2bf(v1.z); a[7] = f2bf(v1.w);
    efrag[ks] = a;
  }

  // ---- GEMM2' (swapped): lane (quad,lm) -> H[edge w*16+lm][n=c*16+quad*4+r4]
  f32x4 h2[8];
#pragma unroll
  for (int c = 0; c < 8; ++c) h2[c] = (f32x4){0.f, 0.f, 0.f, 0.f};
#pragma unroll
  for (int ks = 0; ks < 4; ++ks) {
    const int fb = (ks * 64 + quad * 16) ^ rswz;
#pragma unroll
    for (int c = 0; c < 8; ++c) {
      bf16x8 wf = *(const bf16x8*)((const char*)Wb + (c * 16 + lm) * 256 + fb);
      h2[c] = __builtin_amdgcn_mfma_f32_16x16x32_bf16(wf, efrag[ks], h2[c], 0, 0, 0);
    }
  }
  __syncthreads();                   // #2: W1 reads done

  stageW(W2T, Wb, tid);              // restage; pack below overlaps (reg-only)

  // bias + relu + pack to bf16 pairs: pk[c][r2] holds n = c*16+quad*4+{2r2,2r2+1}
  int pk[8][2];
#pragma unroll
  for (int c = 0; c < 8; ++c) {
    float4 be = *(const float4*)(b_e1 + c * 16 + quad * 4);
    float v0 = h2[c][0] + be.x; v0 = v0 > 0.f ? v0 : 0.f;
    float v1 = h2[c][1] + be.y; v1 = v1 > 0.f ? v1 : 0.f;
    float v2 = h2[c][2] + be.z; v2 = v2 > 0.f ? v2 : 0.f;
    float v3 = h2[c][3] + be.w; v3 = v3 > 0.f ? v3 : 0.f;
    pk[c][0] = (int)f2bf(v0) | ((int)f2bf(v1) << 16);
    pk[c][1] = (int)f2bf(v2) | ((int)f2bf(v3) << 16);
  }
  __syncthreads();                   // #3: W2 staged

  f32x4 msg[8];
#pragma unroll
  for (int c = 0; c < 8; ++c) msg[c] = (f32x4){0.f, 0.f, 0.f, 0.f};

  // ---- GEMM3: msg = relu(H) @ W2. A-frag k=ks*32+quad*8+j gathered from
  // quad-mates: c'=2ks+(quad>>1), src lane (2*(quad&1)+(j>>2))*16+lm.
  const int sa = ((quad & 1) << 5) + lm;
  const int sb = sa + 16;
  const bool chi = ((quad >> 1) & 1) != 0;
#pragma unroll
  for (int ks = 0; ks < 4; ++ks) {
    int a0 = __shfl(pk[2 * ks][0], sa),     a1 = __shfl(pk[2 * ks][1], sa);
    int a2 = __shfl(pk[2 * ks][0], sb),     a3 = __shfl(pk[2 * ks][1], sb);
    int b0 = __shfl(pk[2 * ks + 1][0], sa), b1 = __shfl(pk[2 * ks + 1][1], sa);
    int b2 = __shfl(pk[2 * ks + 1][0], sb), b3 = __shfl(pk[2 * ks + 1][1], sb);
    union { int4 i; bf16x8 v; } cv;
    cv.i = chi ? (int4){b0, b1, b2, b3} : (int4){a0, a1, a2, a3};
    bf16x8 af = cv.v;
    const int fb = (ks * 64 + quad * 16) ^ rswz;
#pragma unroll
    for (int c = 0; c < 8; ++c) {
      bf16x8 wf = *(const bf16x8*)((const char*)Wb + (c * 16 + lm) * 256 + fb);
      msg[c] = __builtin_amdgcn_mfma_f32_16x16x32_bf16(af, wf, msg[c], 0, 0, 0);
    }
  }
  __syncthreads();                   // #4: W2 reads done

  // ---- GEMM1: typed transform; stage + masked pass per type present ----
  const int tmask = tmask_s;         // block-uniform
  for (int t = 0; t < 4; ++t) {
    if (!(tmask & (1 << t))) continue;
    stageW(WTt + t * Dd * Dd, Wb, tid);
    __syncthreads();                 // Wt staged
    bool mine = (myt == t);
    if (__any(mine)) {
#pragma unroll
      for (int ks = 0; ks < 4; ++ks) {
        bf16x8 a = mine ? ax[ks] : (bf16x8){0, 0, 0, 0, 0, 0, 0, 0};
        const int fb = (ks * 64 + quad * 16) ^ rswz;
#pragma unroll
        for (int c = 0; c < 8; ++c) {
          bf16x8 b = *(const bf16x8*)((const char*)Wb + (c * 16 + lm) * 256 + fb);
          msg[c] = __builtin_amdgcn_mfma_f32_16x16x32_bf16(a, b, msg[c], 0, 0, 0);
        }
      }
    }
    __syncthreads();                 // Wb reads done before next restage
  }

  // epilogue: + per-type bias (+b_e2 fused) and atomic scatter to accum[row]
#pragma unroll
  for (int r4 = 0; r4 < 4; ++r4) {
    int m = w * 16 + quad * 4 + r4;
    int rn = mrow[m];
    if (rn < 0) continue;
    int t = mtype[m];
    float* dst = accum + (long long)rn * Dd;
    const float* bc = biasc + t * Dd;
#pragma unroll
    for (int c = 0; c < 8; ++c) {
      int n = c * 16 + lm;
      unsafeAtomicAdd(dst + n, msg[c][r4] + bc[n]);
    }
  }
}

// ---------------- self transform + LayerNorm + ReLU (register LN) -----------
// 32-row tiles, 128 threads (2 waves), LN stats via __shfl_xor over the
// 16-lane group: no S/P/MU LDS, 1 barrier instead of 4.
__global__ __launch_bounds__(128, 4) void selfln_kernel(
    const unsigned short* __restrict__ xbf, const unsigned short* __restrict__ WsT,
    const float* __restrict__ b_self, const float* __restrict__ accum,
    const float* __restrict__ ln_g, const float* __restrict__ ln_b,
    float* __restrict__ out) {
  __shared__ unsigned short Axl[32][136];

  const int tid = threadIdx.x;
  const int tile0 = blockIdx.x * 32;
  {
    const int r = tid >> 2, c0 = (tid & 3) * 32;
    int row = tile0 + r;
    if (row < Nn) {
      const uint4* xs = (const uint4*)(xbf + row * Dd + c0);
      uint4* xd = (uint4*)&Axl[r][c0];
      xd[0] = xs[0]; xd[1] = xs[1]; xd[2] = xs[2]; xd[3] = xs[3];
    } else {
      uint4 z = {0, 0, 0, 0};
      uint4* xd = (uint4*)&Axl[r][c0];
      xd[0] = z; xd[1] = z; xd[2] = z; xd[3] = z;
    }
  }
  __syncthreads();

  const int w = tid >> 6, l = tid & 63, quad = l >> 4, lm = l & 15;
  const int mr = w * 16 + lm;
  f32x4 acc[8];
#pragma unroll
  for (int c = 0; c < 8; ++c) acc[c] = (f32x4){0.f, 0.f, 0.f, 0.f};
#pragma unroll
  for (int ks = 0; ks < 4; ++ks) {
    bf16x8 a = *(const bf16x8*)&Axl[mr][ks * 32 + quad * 8];
#pragma unroll
    for (int c = 0; c < 8; ++c) {
      bf16x8 b = *(const bf16x8*)(WsT + (c * 16 + lm) * Dd + ks * 32 + quad * 8);
      acc[c] = __builtin_amdgcn_mfma_f32_16x16x32_bf16(a, b, acc[c], 0, 0, 0);
    }
  }

  // + b_self + accum; accumulate row stats in registers
  float s1[4] = {0.f, 0.f, 0.f, 0.f}, s2[4] = {0.f, 0.f, 0.f, 0.f};
#pragma unroll
  for (int c = 0; c < 8; ++c) {
    int n = c * 16 + lm;
    float bs = b_self[n];
#pragma unroll
    for (int r4 = 0; r4 < 4; ++r4) {
      int grow = tile0 + w * 16 + quad * 4 + r4;
      float v = acc[c][r4] + bs;
      if (grow < Nn) v += accum[(long long)grow * Dd + n];
      acc[c][r4] = v;
      s1[r4] += v;
      s2[r4] += v * v;
    }
  }
  // reduce across the 16 lanes (lm) of this quad-group
#pragma unroll
  for (int off = 1; off < 16; off <<= 1) {
#pragma unroll
    for (int r4 = 0; r4 < 4; ++r4) {
      s1[r4] += __shfl_xor(s1[r4], off);
      s2[r4] += __shfl_xor(s2[r4], off);
    }
  }
  float mu[4], rs[4];
#pragma unroll
  for (int r4 = 0; r4 < 4; ++r4) {
    mu[r4] = s1[r4] * (1.f / 128.f);
    float var = s2[r4] * (1.f / 128.f) - mu[r4] * mu[r4];
    rs[r4] = rsqrtf(var + 1e-5f);
  }
  // normalize + affine + relu + store
#pragma unroll
  for (int c = 0; c < 8; ++c) {
    int n = c * 16 + lm;
    float g = ln_g[n], bb = ln_b[n];
#pragma unroll
    for (int r4 = 0; r4 < 4; ++r4) {
      int grow = tile0 + w * 16 + quad * 4 + r4;
      if (grow < Nn) {
        float v = (acc[c][r4] - mu[r4]) * rs[r4] * g + bb;
        out[(long long)grow * Dd + n] = v > 0.f ? v : 0.f;
      }
    }
  }
}

// ---------------- launch ----------------------------------------------------
extern "C" void kernel_launch(void* const* d_in, const int* in_sizes, int n_in,
                              void* d_out, int out_size, void* d_ws, size_t ws_size,
                              hipStream_t stream) {
  (void)in_sizes; (void)n_in; (void)out_size; (void)ws_size;
  const float* x       = (const float*)d_in[0];
  const int*   eidx    = (const int*)d_in[1];
  const int*   etype   = (const int*)d_in[2];
  const float* ef      = (const float*)d_in[3];
  const float* W_types = (const float*)d_in[4];
  const float* b_types = (const float*)d_in[5];
  const float* W_self  = (const float*)d_in[6];
  const float* b_self  = (const float*)d_in[7];
  const float* W_e1    = (const float*)d_in[8];
  const float* b_e1    = (const float*)d_in[9];
  const float* W_e2    = (const float*)d_in[10];
  const float* b_e2    = (const float*)d_in[11];
  const float* ln_g    = (const float*)d_in[12];
  const float* ln_b    = (const float*)d_in[13];
  float* out = (float*)d_out;

  char* ws = (char*)d_ws;
  // layout (all offsets 512B-aligned)
  int*            ints   = (int*)ws;                              // [0..3] hist, [4..7] cursor
  float*          accum  = (float*)(ws + 512);                    // N*D f32 = 25,600,000 B
  unsigned short* xbf    = (unsigned short*)(ws + 512 + 25600000);            // 12,800,000 B
  unsigned short* WTt    = (unsigned short*)(ws + 512 + 25600000 + 12800000); // 131,072 B
  unsigned short* W1T    = WTt + 4 * 128 * 128;
  unsigned short* W2T    = W1T + 128 * 128;
  unsigned short* WsT    = W2T + 128 * 128;
  float*          biasc  = (float*)(WsT + 128 * 128);             // 2,048 B
  int*            sorted = (int*)((char*)biasc + 2048);           // E*4 = 2,000,000 B

  hipMemsetAsync(ws, 0, 512 + (size_t)Nn * Dd * 4, stream);  // hist+cursor+accum

  prep_kernel<<<25450, 256, 0, stream>>>(x, W_types, b_types, W_self, W_e1, W_e2,
                                         b_e2, xbf, WTt, W1T, W2T, WsT, biasc);
  hist_kernel<<<512, 256, 0, stream>>>(etype, ints);
  prefix_kernel<<<1, 64, 0, stream>>>(ints, ints + 4);
  scatter_kernel<<<512, 256, 0, stream>>>(etype, ints + 4, sorted);
  edge_kernel<<<(Ee + 63) / 64, 256, 0, stream>>>(eidx, etype, ef, xbf, WTt, W1T,
                                                  W2T, biasc, b_e1, sorted, accum);
  selfln_kernel<<<(Nn + 31) / 32, 128, 0, stream>>>(xbf, WsT, b_self, accum, ln_g,
                                                    ln_b, out);
}